// Round 8
// baseline (2323.109 us; speedup 1.0000x reference)
//
#include <hip/hip_runtime.h>
#include <math.h>

// Problem constants (B, T, D_IN, D_OUT) = (64, 1024, 512, 512)
#define BATCH   64
#define TSTEPS  1024
#define DIN     512
#define DH      512
#define MDIM    (BATCH * TSTEPS)
#define MB      16

// K2 LDS layout: [8 waves][15 chunks][1024 B] packed B + 2 x 16 KiB H
#define BLDS_W   15360
#define BLDS_ALL 122880
#define K2_LDS   (BLDS_ALL + 2 * 16384)   // 155648 <= 163840

typedef _Float16 f16x8 __attribute__((ext_vector_type(8)));
typedef float    f32x4 __attribute__((ext_vector_type(4)));

__device__ inline unsigned short f2h_bits(float x) {
    _Float16 h = (_Float16)x;
    return __builtin_bit_cast(unsigned short, h);
}
// fast tanh: 1 - 2/(exp2(2x*log2e)+1); saturates correctly incl. inf
__device__ inline float ftanh(float x) {
    float e = __builtin_amdgcn_exp2f(x * 2.88539008177792681472f);
    return 1.0f - 2.0f * __builtin_amdgcn_rcpf(e + 1.0f);
}

// ---------------------------------------------------------------------------
// K1a: convert x (fp32) -> Xh (fp16)
// ---------------------------------------------------------------------------
__global__ __launch_bounds__(256) void convert_x(const float* __restrict__ x,
                                                 _Float16* __restrict__ xh,
                                                 int nvec) {
    int i = blockIdx.x * blockDim.x + threadIdx.x;
    int stride = gridDim.x * blockDim.x;
    for (; i < nvec; i += stride) {
        const float4* p = (const float4*)x + 2 * (size_t)i;
        float4 a = p[0], b = p[1];
        f16x8 o = { (_Float16)a.x, (_Float16)a.y, (_Float16)a.z, (_Float16)a.w,
                    (_Float16)b.x, (_Float16)b.y, (_Float16)b.z, (_Float16)b.w };
        ((f16x8*)xh)[i] = o;
    }
}

// ---------------------------------------------------------------------------
// K1b: Wt[n][k] = (fp16) W[k][n]   (also reused for Wr)
// ---------------------------------------------------------------------------
__global__ __launch_bounds__(256) void transpose_w(const float* __restrict__ W,
                                                   _Float16* __restrict__ Wt) {
    __shared__ float tile[64][65];
    const int t  = threadIdx.x;
    const int c  = t & 63;
    const int r0 = t >> 6;
    const int bn = blockIdx.x & 7;
    const int bk = blockIdx.x >> 3;
    const int k0 = bk * 64, n0 = bn * 64;
    #pragma unroll
    for (int i = 0; i < 16; ++i)
        tile[r0 + 4 * i][c] = W[(size_t)(k0 + r0 + 4 * i) * DH + n0 + c];
    __syncthreads();
    #pragma unroll
    for (int i = 0; i < 16; ++i)
        Wt[(size_t)(n0 + r0 + 4 * i) * DIN + k0 + c] = (_Float16)tile[c][r0 + 4 * i];
}

// ---------------------------------------------------------------------------
// K1d: pack slice-3 B-fragments (cols wv*64+48 .. +63) fragment-contiguous:
//   Wrp[wv*1024 + c*64 + lane] = frag (f16x8). Scan keeps chunks 0..14 in
//   LDS and streams chunk 15 from L2 each step.
// ---------------------------------------------------------------------------
__global__ __launch_bounds__(512) void pack_b3(const _Float16* __restrict__ Wrt,
                                               _Float16* __restrict__ Wrp) {
    const int i  = blockIdx.x * 512 + threadIdx.x;   // 0..8191
    const int wv = i >> 10;
    const int c  = (i >> 6) & 15;
    const int l  = i & 63;
    const int col = wv * 64 + 48 + (l & 15);
    const int k0  = c * 32 + (l >> 4) * 8;
    ((f16x8*)Wrp)[i] = *(const f16x8*)&Wrt[(size_t)col * DIN + k0];
}

// ---------------------------------------------------------------------------
// K1c: XW = Xh @ Wt^T + bias via mfma_f32_16x16x32_f16 (validated earlier)
// ---------------------------------------------------------------------------
__global__ __launch_bounds__(256) void gemm_xw_mfma(const _Float16* __restrict__ Xh,
                                                    const _Float16* __restrict__ Wt,
                                                    const float* __restrict__ bias,
                                                    float* __restrict__ XW) {
    __shared__ __align__(16) _Float16 Ah[128][32];
    __shared__ __align__(16) _Float16 Bh[128][32];

    const int tid  = threadIdx.x;
    const int wv   = tid >> 6;
    const int lane = tid & 63;
    const int bn   = blockIdx.x & 3;
    const int bm   = blockIdx.x >> 2;
    const int m0   = bm * 128;
    const int n0   = bn * 128;

    const int mbase = (wv >> 1) * 64;
    const int nbase = (wv & 1) * 64;
    const int fr    = lane & 15;
    const int fq    = lane >> 4;

    f32x4 acc[4][4];
    #pragma unroll
    for (int i = 0; i < 4; ++i)
        #pragma unroll
        for (int j = 0; j < 4; ++j)
            acc[i][j] = (f32x4){0.f, 0.f, 0.f, 0.f};

    for (int kc = 0; kc < DIN / 32; ++kc) {
        const int k0 = kc * 32;
#if __has_builtin(__builtin_amdgcn_global_load_lds)
        #pragma unroll
        for (int q = 0; q < 2; ++q) {
            const int rb = wv * 2 + q;
            const int gr = (rb * 16) + (lane >> 2);
            const int gc = (lane & 3) * 8;
            const _Float16* ga = Xh + (size_t)(m0 + gr) * DIN + k0 + gc;
            const _Float16* gb = Wt + (size_t)(n0 + gr) * DIN + k0 + gc;
            __builtin_amdgcn_global_load_lds(
                (const __attribute__((address_space(1))) void*)ga,
                (__attribute__((address_space(3))) void*)&Ah[rb * 16][0], 16, 0, 0);
            __builtin_amdgcn_global_load_lds(
                (const __attribute__((address_space(1))) void*)gb,
                (__attribute__((address_space(3))) void*)&Bh[rb * 16][0], 16, 0, 0);
        }
#else
        #pragma unroll
        for (int q = 0; q < 2; ++q) {
            const int h0 = (q * 256 + tid) * 8;
            const int row = h0 >> 5, col = h0 & 31;
            *((uint4*)Ah + (q * 256 + tid)) =
                *(const uint4*)(Xh + (size_t)(m0 + row) * DIN + k0 + col);
            *((uint4*)Bh + (q * 256 + tid)) =
                *(const uint4*)(Wt + (size_t)(n0 + row) * DIN + k0 + col);
        }
#endif
        __syncthreads();

        f16x8 af[4], bf[4];
        #pragma unroll
        for (int mt = 0; mt < 4; ++mt)
            af[mt] = *(const f16x8*)&Ah[mbase + mt * 16 + fr][fq * 8];
        #pragma unroll
        for (int nt = 0; nt < 4; ++nt)
            bf[nt] = *(const f16x8*)&Bh[nbase + nt * 16 + fr][fq * 8];
        #pragma unroll
        for (int mt = 0; mt < 4; ++mt)
            #pragma unroll
            for (int nt = 0; nt < 4; ++nt)
                acc[mt][nt] = __builtin_amdgcn_mfma_f32_16x16x32_f16(
                    af[mt], bf[nt], acc[mt][nt], 0, 0, 0);
        __syncthreads();
    }

    #pragma unroll
    for (int nt = 0; nt < 4; ++nt) {
        const int col = n0 + nbase + nt * 16 + fr;
        const float bvl = bias[col];
        #pragma unroll
        for (int mt = 0; mt < 4; ++mt) {
            #pragma unroll
            for (int r = 0; r < 4; ++r) {
                const int row = m0 + mbase + mt * 16 + fq * 4 + r;
                XW[(size_t)row * DH + col] = acc[mt][nt][r] + bvl;
            }
        }
    }
}

// ---------------------------------------------------------------------------
// K1 fallback (fp32 VALU GEMM)
// ---------------------------------------------------------------------------
__global__ __launch_bounds__(256) void gemm_xw(const float* __restrict__ X,
                                               const float* __restrict__ W,
                                               const float* __restrict__ bias,
                                               float* __restrict__ XW) {
    __shared__ float As[16][68];
    __shared__ float Bs[16][68];
    const int tid = threadIdx.x;
    const int bx  = blockIdx.x & 7;
    const int by  = blockIdx.x >> 3;
    const int m0  = by * 64, n0 = bx * 64;
    const int ty = tid >> 4, tx = tid & 15;
    const int arow = tid >> 2, akq = (tid & 3) * 4;
    const int brow = tid >> 4, bcq = (tid & 15) * 4;
    float acc[4][4] = {{0.f}};
    for (int k0 = 0; k0 < DIN; k0 += 16) {
        float4 av = *(const float4*)&X[(size_t)(m0 + arow) * DIN + k0 + akq];
        float4 bv = *(const float4*)&W[(size_t)(k0 + brow) * DH + n0 + bcq];
        __syncthreads();
        As[akq + 0][arow] = av.x; As[akq + 1][arow] = av.y;
        As[akq + 2][arow] = av.z; As[akq + 3][arow] = av.w;
        *(float4*)&Bs[brow][bcq] = bv;
        __syncthreads();
        #pragma unroll
        for (int k = 0; k < 16; ++k) {
            float4 a = *(const float4*)&As[k][ty * 4];
            float4 b = *(const float4*)&Bs[k][tx * 4];
            float ar[4] = {a.x, a.y, a.z, a.w};
            float br[4] = {b.x, b.y, b.z, b.w};
            #pragma unroll
            for (int i = 0; i < 4; ++i)
                #pragma unroll
                for (int j = 0; j < 4; ++j)
                    acc[i][j] = fmaf(ar[i], br[j], acc[i][j]);
        }
    }
    float4 bv = *(const float4*)&bias[n0 + tx * 4];
    const float br[4] = {bv.x, bv.y, bv.z, bv.w};
    #pragma unroll
    for (int i = 0; i < 4; ++i) {
        float4 o;
        o.x = acc[i][0] + br[0]; o.y = acc[i][1] + br[1];
        o.z = acc[i][2] + br[2]; o.w = acc[i][3] + br[3];
        *(float4*)&XW[(size_t)(m0 + ty * 4 + i) * DH + n0 + tx * 4] = o;
    }
}

// ---------------------------------------------------------------------------
// K2: round-5 structure + SWAPPED MFMA OPERANDS (transposed C-frag).
// mfma(A=Wr-frag, B=H-frag) computes D'[col][batch]: for 16x16x32, the A-
// and B-frag lane layouts are the same "[lane&15][ (lane>>4)*8+j ]" pattern,
// so breg/af load code is UNCHANGED -- only the call order and epilogue
// interpretation change. C-frag now gives each thread ONE batch (fr) and
// 4 CONSECUTIVE cols (fq*4+r) per slice:
//   - epilogue: 16 ds_write_b16 -> 4 ds_write_b64 (packed 2xu16 per u32)
//   - xv:       16 scalar dwords -> 4 float4 loads (64B segments)
//   DS instrs/CU/step 376 -> 280; VMEM instrs/wave 17 -> 5.
// Everything else is the proven round-5 kernel: slices 0..2 in regs (192),
// slice-3 chunks 0..14 LDS fragment-packed, chunk 15 streamed from L2
// (laundered "+v"), fragment-linear H, double-buffer, ONE barrier/step.
// ---------------------------------------------------------------------------
__global__ __launch_bounds__(512, 1) void rnn_scan_swp(const float* __restrict__ XW,
                                                       const _Float16* __restrict__ Wrt,
                                                       const _Float16* __restrict__ Wrp,
                                                       float* __restrict__ Hout) {
    extern __shared__ __align__(16) char lds[];
    char* bwl   = lds;                 // [8 waves][15 chunks][1024 B]
    char* Hbase = lds + BLDS_ALL;      // 2 x 16384 B, fragment-linear

    const int tid  = threadIdx.x;
    const int wv   = tid >> 6;        // wave 0..7, owns cols [wv*64, wv*64+64)
    const int lane = tid & 63;
    const int fr   = lane & 15;
    const int fq   = lane >> 4;
    const int b0   = blockIdx.x * MB;

    // h0 = 0 (buffer 0 only)
    for (int i = tid; i < 4096; i += 512) ((unsigned int*)Hbase)[i] = 0u;

    // ---- one-time preload: slices 0..2 -> registers (192 regs) ----
    f16x8 breg[3][16];
    #pragma unroll
    for (int s = 0; s < 3; ++s) {
        const int col = wv * 64 + s * 16 + fr;
        #pragma unroll
        for (int c = 0; c < 16; ++c)
            breg[s][c] = *(const f16x8*)&Wrt[(size_t)col * DH + c * 32 + fq * 8];
    }
    // ---- one-time preload: slice-3 chunks 0..14 -> LDS, fragment-packed ----
    {
        const f16x8* src = (const f16x8*)Wrp + wv * 1024 + lane;
        char* dst = bwl + wv * BLDS_W + lane * 16;
        #pragma unroll
        for (int c = 0; c < 15; ++c)
            *(f16x8*)(dst + c * 1024) = src[c * 64];
    }
    __syncthreads();

    // xv: batch = fr, cols wv*64 + s*16 + fq*4 .. +4 (float4 per slice)
    const float* xbase = XW + (size_t)(b0 + fr) * TSTEPS * DH + wv * 64 + fq * 4;
    const f16x8* b15   = (const f16x8*)Wrp + wv * 1024 + 15 * 64 + lane;
    const char*  bw    = bwl + wv * BLDS_W + lane * 16;

    // epilogue b64 write base (half units), derived from the fragment-linear
    // H mapping for col = wv*64 + s*16 + fq*4 + r, row = fr:
    //   half = (2wv + (s>>1))*512 + ((2(s&1) + (fq>>1))*16 + fr)*8 + (fq&1)*4 + r
    const int ebase = wv * 1024 + ((fq >> 1) * 16 + fr) * 8 + (fq & 1) * 4;

    #pragma unroll 1
    for (int t = 0; t < TSTEPS; ++t) {
        const char* Hr = Hbase + ((t & 1) << 14);
        char*       Hw = Hbase + (((t + 1) & 1) << 14);

        // chunk-15 B stream (stays a per-step hidden L2 load; round-5 proven)
        int toff = 0;
        asm volatile("" : "+v"(toff));
        f16x8 bs = b15[toff];

        // xw for this step: 4 coalesced float4 loads (was 16 scalar dwords)
        float4 xv[4];
        #pragma unroll
        for (int s = 0; s < 4; ++s)
            xv[s] = *(const float4*)(xbase + (size_t)t * DH + s * 16);

        f32x4 cc[4];
        #pragma unroll
        for (int s = 0; s < 4; ++s) cc[s] = (f32x4){0.f, 0.f, 0.f, 0.f};

        // chunks 0..14: A(=Wr frags) x B(=H frag), operands SWAPPED
        #pragma unroll
        for (int c = 0; c < 15; ++c) {
            f16x8 hf = *(const f16x8*)(Hr + c * 1024 + lane * 16);
            f16x8 bf = *(const f16x8*)(bw + c * 1024);
            cc[0] = __builtin_amdgcn_mfma_f32_16x16x32_f16(breg[0][c], hf, cc[0], 0, 0, 0);
            cc[1] = __builtin_amdgcn_mfma_f32_16x16x32_f16(breg[1][c], hf, cc[1], 0, 0, 0);
            cc[2] = __builtin_amdgcn_mfma_f32_16x16x32_f16(breg[2][c], hf, cc[2], 0, 0, 0);
            cc[3] = __builtin_amdgcn_mfma_f32_16x16x32_f16(bf,         hf, cc[3], 0, 0, 0);
        }
        {
            f16x8 hf = *(const f16x8*)(Hr + 15 * 1024 + lane * 16);
            cc[0] = __builtin_amdgcn_mfma_f32_16x16x32_f16(breg[0][15], hf, cc[0], 0, 0, 0);
            cc[1] = __builtin_amdgcn_mfma_f32_16x16x32_f16(breg[1][15], hf, cc[1], 0, 0, 0);
            cc[2] = __builtin_amdgcn_mfma_f32_16x16x32_f16(breg[2][15], hf, cc[2], 0, 0, 0);
            cc[3] = __builtin_amdgcn_mfma_f32_16x16x32_f16(bs,          hf, cc[3], 0, 0, 0);
        }

        // epilogue: h = tanh(cc + xv); 4 packed b64 LDS writes (was 16 b16)
        unsigned short* hsh = (unsigned short*)Hw;
        #pragma unroll
        for (int s = 0; s < 4; ++s) {
            const unsigned int w0 =
                (unsigned int)f2h_bits(ftanh(cc[s][0] + xv[s].x)) |
                ((unsigned int)f2h_bits(ftanh(cc[s][1] + xv[s].y)) << 16);
            const unsigned int w1 =
                (unsigned int)f2h_bits(ftanh(cc[s][2] + xv[s].z)) |
                ((unsigned int)f2h_bits(ftanh(cc[s][3] + xv[s].w)) << 16);
            uint2 v; v.x = w0; v.y = w1;
            *(uint2*)(hsh + ebase + (s >> 1) * 512 + (s & 1) * 256) = v;
        }
        __syncthreads();   // Hw complete before next step reads it
    }

    // final output: H_T in buffer 0 (TSTEPS even). Coalesced float4 stores.
    {
        const int m  = tid >> 5;           // 0..15
        const int cg = tid & 31;           // 16-col group
        const int cb = cg * 16;
        const int c  = cg >> 1;            // chunk
        const int fb = (cg & 1) * 2;       // fq' base
        const char* Hb0 = Hbase;
        #pragma unroll
        for (int g = 0; g < 2; ++g) {
            f16x8 v = *(const f16x8*)(Hb0 + c * 1024 + ((fb + g) * 16 + m) * 16);
            float4 o0 = { (float)v[0], (float)v[1], (float)v[2], (float)v[3] };
            float4 o1 = { (float)v[4], (float)v[5], (float)v[6], (float)v[7] };
            *(float4*)&Hout[(size_t)(b0 + m) * DH + cb + g * 8]     = o0;
            *(float4*)&Hout[(size_t)(b0 + m) * DH + cb + g * 8 + 4] = o1;
        }
    }
}

// ---------------------------------------------------------------------------
// launch
// ---------------------------------------------------------------------------
extern "C" void kernel_launch(void* const* d_in, const int* in_sizes, int n_in,
                              void* d_out, int out_size, void* d_ws, size_t ws_size,
                              hipStream_t stream) {
    const float* x  = (const float*)d_in[0];
    const float* W  = (const float*)d_in[1];
    const float* Wr = (const float*)d_in[2];
    const float* bv = (const float*)d_in[3];
    float* out = (float*)d_out;

    const size_t XW_BYTES  = (size_t)MDIM * DH * sizeof(float);     // 128 MiB
    const size_t WRT_BYTES = (size_t)DH * DH * sizeof(_Float16);    // 512 KiB
    const size_t WRP_BYTES = (size_t)8 * 16 * 64 * 8 * sizeof(_Float16); // 128 KiB
    const size_t XH_BYTES  = (size_t)MDIM * DIN * sizeof(_Float16); // 64 MiB
    const size_t WT_BYTES  = (size_t)DIN * DH * sizeof(_Float16);   // 512 KiB

    const size_t SCAN_MIN = XW_BYTES + WRT_BYTES + WRP_BYTES;
    if (ws_size < SCAN_MIN) return;

    char* base = (char*)d_ws;
    float*    xw  = (float*)base;
    _Float16* wrt = (_Float16*)(base + XW_BYTES);
    _Float16* wrp = (_Float16*)(base + XW_BYTES + WRT_BYTES);

    hipFuncSetAttribute((const void*)rnn_scan_swp,
                        hipFuncAttributeMaxDynamicSharedMemorySize, K2_LDS);

    transpose_w<<<dim3(64), dim3(256), 0, stream>>>(Wr, wrt);
    pack_b3<<<dim3(16), dim3(512), 0, stream>>>(wrt, wrp);

    if (ws_size >= SCAN_MIN + XH_BYTES + WT_BYTES) {
        _Float16* xh = (_Float16*)(base + SCAN_MIN);
        _Float16* wt = (_Float16*)(base + SCAN_MIN + XH_BYTES);
        convert_x<<<dim3(2048), dim3(256), 0, stream>>>(x, xh, MDIM * DIN / 8);
        transpose_w<<<dim3(64), dim3(256), 0, stream>>>(W, wt);
        gemm_xw_mfma<<<dim3((MDIM / 128) * (DH / 128)), dim3(256), 0, stream>>>(
            xh, wt, bv, xw);
    } else {
        gemm_xw<<<dim3((MDIM / 64) * (DH / 64)), dim3(256), 0, stream>>>(x, W, bv, xw);
    }

    rnn_scan_swp<<<dim3(BATCH / MB), dim3(512), K2_LDS, stream>>>(xw, wrt, wrp, out);
}